// Round 13
// baseline (527.641 us; speedup 1.0000x reference)
//
#include <hip/hip_runtime.h>
#include <cstddef>
#include <cstdint>

// Problem constants
#define Bb 4
#define Tt 4096
#define Dd 1024
#define Hh 16
#define HDd 64
#define NSs 64
#define SPHh 4
#define HMm 4096
#define MTOK (Bb*Tt)   // 16384

typedef _Float16 f16x8 __attribute__((ext_vector_type(8)));
typedef _Float16 f16x4 __attribute__((ext_vector_type(4)));
typedef float f32x4 __attribute__((ext_vector_type(4)));

__device__ __forceinline__ float gelu_f(float x) {
    return 0.5f * x * (1.0f + erff(x * 0.70710678118654752440f));
}

// XCD-chunked bijective block swizzle (requires nwg % 8 == 0; all launches comply)
__device__ __forceinline__ int xcd_swz(int nwg) {
    int orig = blockIdx.y * gridDim.x + blockIdx.x;
    int cpx = nwg >> 3;
    return (orig & 7) * cpx + (orig >> 3);
}

// ---------------- K0: cb partials ----------------
__global__ __launch_bounds__(256) void cb_part_k(const float* __restrict__ slot_init,
                                                 const float* __restrict__ rw1,
                                                 float* __restrict__ cbp) {
    __shared__ float sm[64];
    int tid = threadIdx.x;
    if (tid < 64) {
        float s = 0.f;
        for (int i = 0; i < 64; ++i) s += slot_init[i * 64 + tid];
        sm[tid] = s * (1.0f / 64.0f);
    }
    __syncthreads();
    int j = blockIdx.x * 256 + tid;
    int k0 = blockIdx.y * 64;
    float acc = 0.f;
#pragma unroll 8
    for (int k = 0; k < 64; ++k)
        acc = fmaf(sm[k], rw1[(size_t)(1024 + k0 + k) * 1024 + j], acc);
    cbp[(size_t)blockIdx.y * 1024 + j] = acc;
}

__global__ __launch_bounds__(256) void cb_comb_k(const float* __restrict__ cbp,
                                                 float* __restrict__ cb) {
    int j = blockIdx.x * 256 + threadIdx.x;
    float acc = 0.f;
#pragma unroll
    for (int c = 0; c < 16; ++c) acc += cbp[(size_t)c * 1024 + j];
    cb[j] = acc;
}

// ---------------- K1: rw1[:1024] -> transposed split-f16 planes ----------------
__global__ __launch_bounds__(256) void wsplitT_k(const float* __restrict__ rw1,
                                                 _Float16* __restrict__ whiT,
                                                 _Float16* __restrict__ wloT) {
    __shared__ float t[32][33];
    int n0 = blockIdx.x * 32, k0 = blockIdx.y * 32;
    int tx = threadIdx.x & 31, ty = threadIdx.x >> 5;
#pragma unroll
    for (int i = 0; i < 32; i += 8)
        t[ty + i][tx] = rw1[(size_t)(k0 + ty + i) * 1024 + n0 + tx];
    __syncthreads();
#pragma unroll
    for (int i = 0; i < 32; i += 8) {
        float v = t[tx][ty + i];
        _Float16 h = (_Float16)v;
        _Float16 l = (_Float16)(v - (float)h);
        whiT[(size_t)(n0 + ty + i) * 1024 + k0 + tx] = h;
        wloT[(size_t)(n0 + ty + i) * 1024 + k0 + tx] = l;
    }
}

// ---------------- K1a: x -> split f16 hi/lo planes ----------------
__global__ __launch_bounds__(256) void xsplit_k(const float* __restrict__ x,
                                                _Float16* __restrict__ xhi,
                                                _Float16* __restrict__ xlo) {
    size_t i = ((size_t)blockIdx.x * 256 + threadIdx.x) * 8;
    float4 a = *(const float4*)(x + i);
    float4 b = *(const float4*)(x + i + 4);
    float v[8] = {a.x, a.y, a.z, a.w, b.x, b.y, b.z, b.w};
    f16x8 h, l;
#pragma unroll
    for (int j = 0; j < 8; ++j) {
        _Float16 hv = (_Float16)v[j];
        h[j] = hv;
        l[j] = (_Float16)(v[j] - (float)hv);
    }
    *(f16x8*)(xhi + i) = h;
    *(f16x8*)(xlo + i) = l;
}

// ---------------- K1b: deep-pipelined split-fp16 routing GEMM ----------------
// 256x256 tile, BK=32, ring-2, counted vmcnt, 4-phase (hgemm8-mirror skeleton).
__global__ __launch_bounds__(512, 2) void hgemm4p_k(const _Float16* __restrict__ Ah,
                                                    const _Float16* __restrict__ Al,
                                                    const _Float16* __restrict__ Bh,
                                                    const _Float16* __restrict__ Bl,
                                                    const float* __restrict__ bias1,
                                                    const float* __restrict__ bias2,
                                                    float* __restrict__ C,
                                                    int M, int N, int K) {
    __shared__ __align__(16) _Float16 Ahs[2][256][32];
    __shared__ __align__(16) _Float16 Als[2][256][32];
    __shared__ __align__(16) _Float16 Bhs[2][256][32];
    __shared__ __align__(16) _Float16 Bls[2][256][32];
    const int tid = threadIdx.x;
    const int wid = tid >> 6;            // 0..7
    const int lane = tid & 63;
    const int swz = xcd_swz(gridDim.x * gridDim.y);
    const int brow = (swz / gridDim.x) * 256;
    const int bcol = (swz % gridDim.x) * 256;
    const int wm = wid >> 2;             // 0..1
    const int wn = wid & 3;              // 0..3

    const int srow = lane >> 2;
    const int scol = ((lane & 3) ^ ((lane >> 3) & 3)) * 8;
    const int fr = lane & 15;
    const int fkp = (((lane >> 4) ^ ((lane >> 1) & 3))) * 8;
    const int crow = (lane >> 4) * 4;

    const int nk = K >> 5;   // 32

    f32x4 acc[8][4];
#pragma unroll
    for (int m = 0; m < 8; ++m)
#pragma unroll
        for (int n = 0; n < 4; ++n)
            acc[m][n] = f32x4{0.f, 0.f, 0.f, 0.f};

    auto stage = [&](int t) {
        const int slot = t & 1;
        const size_t kk = (size_t)t << 5;
#pragma unroll
        for (int i = 0; i < 2; ++i) {
            int r0 = wid * 32 + i * 16;
            const _Float16* gah = Ah + (size_t)(brow + r0 + srow) * K + kk + scol;
            __builtin_amdgcn_global_load_lds(
                (const __attribute__((address_space(1))) void*)gah,
                (__attribute__((address_space(3))) void*)&Ahs[slot][r0][0], 16, 0, 0);
            const _Float16* gal = Al + (size_t)(brow + r0 + srow) * K + kk + scol;
            __builtin_amdgcn_global_load_lds(
                (const __attribute__((address_space(1))) void*)gal,
                (__attribute__((address_space(3))) void*)&Als[slot][r0][0], 16, 0, 0);
            const _Float16* gbh = Bh + (size_t)(bcol + r0 + srow) * K + kk + scol;
            __builtin_amdgcn_global_load_lds(
                (const __attribute__((address_space(1))) void*)gbh,
                (__attribute__((address_space(3))) void*)&Bhs[slot][r0][0], 16, 0, 0);
            const _Float16* gbl = Bl + (size_t)(bcol + r0 + srow) * K + kk + scol;
            __builtin_amdgcn_global_load_lds(
                (const __attribute__((address_space(1))) void*)gbl,
                (__attribute__((address_space(3))) void*)&Bls[slot][r0][0], 16, 0, 0);
        }
    };

    stage(0);
    if (nk > 1) stage(1);

    for (int t = 0; t < nk; ++t) {
        if (t + 1 < nk) asm volatile("s_waitcnt vmcnt(8)" ::: "memory");
        else            asm volatile("s_waitcnt vmcnt(0)" ::: "memory");
        __builtin_amdgcn_sched_barrier(0);
        __builtin_amdgcn_s_barrier();     // tile t staged by all waves
        __builtin_amdgcn_sched_barrier(0);

        const int slot = t & 1;
        f16x8 afh[4], afl[4], bfh[4], bfl[4];
        // ---- p0: A m0-3 (hi/lo) + B n0-1 (hi/lo); MFMA m0-3 x n0-1 ----
#pragma unroll
        for (int m = 0; m < 4; ++m) {
            afh[m] = *(const f16x8*)&Ahs[slot][wm * 128 + m * 16 + fr][fkp];
            afl[m] = *(const f16x8*)&Als[slot][wm * 128 + m * 16 + fr][fkp];
        }
#pragma unroll
        for (int n = 0; n < 2; ++n) {
            bfh[n] = *(const f16x8*)&Bhs[slot][wn * 64 + n * 16 + fr][fkp];
            bfl[n] = *(const f16x8*)&Bls[slot][wn * 64 + n * 16 + fr][fkp];
        }
        __builtin_amdgcn_sched_barrier(0);
        __builtin_amdgcn_s_barrier();
        asm volatile("s_waitcnt lgkmcnt(0)" ::: "memory");
        __builtin_amdgcn_sched_barrier(0);
        __builtin_amdgcn_s_setprio(1);
#pragma unroll
        for (int m = 0; m < 4; ++m)
#pragma unroll
            for (int n = 0; n < 2; ++n) {
                acc[m][n] = __builtin_amdgcn_mfma_f32_16x16x32_f16(afl[m], bfh[n], acc[m][n], 0, 0, 0);
                acc[m][n] = __builtin_amdgcn_mfma_f32_16x16x32_f16(afh[m], bfl[n], acc[m][n], 0, 0, 0);
                acc[m][n] = __builtin_amdgcn_mfma_f32_16x16x32_f16(afh[m], bfh[n], acc[m][n], 0, 0, 0);
            }
        __builtin_amdgcn_s_setprio(0);
        __builtin_amdgcn_sched_barrier(0);
        // ---- p1: B n2-3; MFMA m0-3 x n2-3 ----
#pragma unroll
        for (int n = 2; n < 4; ++n) {
            bfh[n] = *(const f16x8*)&Bhs[slot][wn * 64 + n * 16 + fr][fkp];
            bfl[n] = *(const f16x8*)&Bls[slot][wn * 64 + n * 16 + fr][fkp];
        }
        __builtin_amdgcn_sched_barrier(0);
        __builtin_amdgcn_s_barrier();
        asm volatile("s_waitcnt lgkmcnt(0)" ::: "memory");
        __builtin_amdgcn_sched_barrier(0);
        __builtin_amdgcn_s_setprio(1);
#pragma unroll
        for (int m = 0; m < 4; ++m)
#pragma unroll
            for (int n = 2; n < 4; ++n) {
                acc[m][n] = __builtin_amdgcn_mfma_f32_16x16x32_f16(afl[m], bfh[n], acc[m][n], 0, 0, 0);
                acc[m][n] = __builtin_amdgcn_mfma_f32_16x16x32_f16(afh[m], bfl[n], acc[m][n], 0, 0, 0);
                acc[m][n] = __builtin_amdgcn_mfma_f32_16x16x32_f16(afh[m], bfh[n], acc[m][n], 0, 0, 0);
            }
        __builtin_amdgcn_s_setprio(0);
        __builtin_amdgcn_sched_barrier(0);
        // ---- p2: A m4-7 (reuse regs); MFMA m4-7 x n0-1 ----
#pragma unroll
        for (int m = 0; m < 4; ++m) {
            afh[m] = *(const f16x8*)&Ahs[slot][wm * 128 + (m + 4) * 16 + fr][fkp];
            afl[m] = *(const f16x8*)&Als[slot][wm * 128 + (m + 4) * 16 + fr][fkp];
        }
        __builtin_amdgcn_sched_barrier(0);
        __builtin_amdgcn_s_barrier();
        asm volatile("s_waitcnt lgkmcnt(0)" ::: "memory");
        __builtin_amdgcn_sched_barrier(0);
        __builtin_amdgcn_s_setprio(1);
#pragma unroll
        for (int m = 0; m < 4; ++m)
#pragma unroll
            for (int n = 0; n < 2; ++n) {
                acc[m + 4][n] = __builtin_amdgcn_mfma_f32_16x16x32_f16(afl[m], bfh[n], acc[m + 4][n], 0, 0, 0);
                acc[m + 4][n] = __builtin_amdgcn_mfma_f32_16x16x32_f16(afh[m], bfl[n], acc[m + 4][n], 0, 0, 0);
                acc[m + 4][n] = __builtin_amdgcn_mfma_f32_16x16x32_f16(afh[m], bfh[n], acc[m + 4][n], 0, 0, 0);
            }
        __builtin_amdgcn_s_setprio(0);
        __builtin_amdgcn_sched_barrier(0);
        // slot fully read by ALL waves past this barrier -> safe to overwrite
        __builtin_amdgcn_s_barrier();
        __builtin_amdgcn_sched_barrier(0);
        // ---- p3: stage t+2 (ring-2), MFMA m4-7 x n2-3 (reg-only) ----
        if (t + 2 < nk) stage(t + 2);
        __builtin_amdgcn_s_setprio(1);
#pragma unroll
        for (int m = 0; m < 4; ++m)
#pragma unroll
            for (int n = 2; n < 4; ++n) {
                acc[m + 4][n] = __builtin_amdgcn_mfma_f32_16x16x32_f16(afl[m], bfh[n], acc[m + 4][n], 0, 0, 0);
                acc[m + 4][n] = __builtin_amdgcn_mfma_f32_16x16x32_f16(afh[m], bfl[n], acc[m + 4][n], 0, 0, 0);
                acc[m + 4][n] = __builtin_amdgcn_mfma_f32_16x16x32_f16(afh[m], bfh[n], acc[m + 4][n], 0, 0, 0);
            }
        __builtin_amdgcn_s_setprio(0);
        __builtin_amdgcn_sched_barrier(0);
    }

#pragma unroll
    for (int m = 0; m < 8; ++m) {
        int row0 = brow + wm * 128 + m * 16 + crow;
#pragma unroll
        for (int n = 0; n < 4; ++n) {
            int col = bcol + wn * 64 + n * 16 + fr;
            float bv = bias1[col] + bias2[col];
#pragma unroll
            for (int r = 0; r < 4; ++r) {
                float v = acc[m][n][r] + bv;
                C[(size_t)(row0 + r) * N + col] = gelu_f(v);
            }
        }
    }
    (void)M;
}

// ---------------- K2: fused route-logits + top-32 + softmax -> alpha ----------------
// Logits computed exactly as logits2_k (bit-identical), kept in LDS; per-wave topk.
__global__ __launch_bounds__(256) void logtop_k(const float* __restrict__ A,
                                                const float* __restrict__ Bw,
                                                const float* __restrict__ rb2,
                                                const float* __restrict__ taup,
                                                float* __restrict__ alpha,
                                                _Float16* __restrict__ alpha16) {
    __shared__ float At[16][68];
    __shared__ float Bs[16][64];
    __shared__ float Lg[64][65];
    const int tid = threadIdx.x;
    const int m0 = blockIdx.x * 64;
    const int rg = tid >> 4;
    const int cg = tid & 15;
    const int srow = tid >> 2;
    const int skk  = (tid & 3) * 4;
    const int bk = tid >> 4;
    const int bc = (tid & 15) * 4;

    float acc[4][4] = {};

    float4 av = *(const float4*)(A + (size_t)(m0 + srow) * 1024 + skk);
    float4 bv = *(const float4*)(Bw + (size_t)bk * 64 + bc);

    for (int k0 = 0; k0 < 1024; k0 += 16) {
        __syncthreads();
        At[skk + 0][srow] = av.x;
        At[skk + 1][srow] = av.y;
        At[skk + 2][srow] = av.z;
        At[skk + 3][srow] = av.w;
        *(float4*)&Bs[bk][bc] = bv;
        __syncthreads();
        if (k0 + 16 < 1024) {
            av = *(const float4*)(A + (size_t)(m0 + srow) * 1024 + k0 + 16 + skk);
            bv = *(const float4*)(Bw + (size_t)(k0 + 16 + bk) * 64 + bc);
        }
#pragma unroll
        for (int k = 0; k < 16; ++k) {
            float4 a4 = *(const float4*)&At[k][rg * 4];
            float4 b4 = *(const float4*)&Bs[k][cg * 4];
            float a[4] = {a4.x, a4.y, a4.z, a4.w};
            float b[4] = {b4.x, b4.y, b4.z, b4.w};
#pragma unroll
            for (int i = 0; i < 4; ++i)
#pragma unroll
                for (int j = 0; j < 4; ++j)
                    acc[i][j] = fmaf(a[i], b[j], acc[i][j]);
        }
    }
    float inv = 1.0f / (fabsf(taup[0]) + 0.1f);
#pragma unroll
    for (int i = 0; i < 4; ++i)
#pragma unroll
        for (int j = 0; j < 4; ++j)
            Lg[rg * 4 + i][cg * 4 + j] = (acc[i][j] + rb2[cg * 4 + j]) * inv;
    __syncthreads();

    // per-wave exact top-32 + softmax over each 64-wide row (tie: lower idx wins)
    const int wave = tid >> 6;
    const int lane = tid & 63;
    const size_t tbase = (size_t)blockIdx.x * 64;
    for (int tt = 0; tt < 16; ++tt) {
        int row = wave * 16 + tt;
        float li = Lg[row][lane];
        float m = li;
#pragma unroll
        for (int off = 32; off; off >>= 1) m = fmaxf(m, __shfl_xor(m, off, 64));
        int cnt = 0;
        for (int off = 1; off < 64; ++off) {
            int j = (lane + off) & 63;
            float lj = __shfl(li, j, 64);
            cnt += (lj > li) || (lj == li && j < lane);
        }
        float e = (cnt < 32) ? expf(li - m) : 0.0f;
        float s = e;
#pragma unroll
        for (int off = 32; off; off >>= 1) s += __shfl_xor(s, off, 64);
        float a = e / s;
        alpha[(tbase + row) * 64 + lane] = a;
        alpha16[(tbase + row) * 64 + lane] = (_Float16)a;
    }
}

// ---------------- K4: slot pooling (reads f16 xhi; value-path tolerance) --------------
__global__ __launch_bounds__(256) void pool_part_k(const _Float16* __restrict__ xh,
                                                   const float* __restrict__ alpha,
                                                   float* __restrict__ part,
                                                   float* __restrict__ partw) {
    int bh = blockIdx.x;
    int c = blockIdx.y;
    int b = bh >> 4, h = bh & 15;
    int tid = threadIdx.x;
    int s = tid >> 6, d = tid & 63;
    __shared__ float lx[16][64];
    __shared__ float la[16][4];
    float acc = 0.f, wacc = 0.f;
    const int tchunk = Tt / 8;
    const int t0base = c * tchunk;
    for (int t0 = 0; t0 < tchunk; t0 += 16) {
        int ttr = tid >> 4;
        int ddr = (tid & 15) * 4;
        size_t trow = (size_t)b * Tt + t0base + t0 + ttr;
        f16x4 xv = *(const f16x4*)(xh + trow * Dd + h * 64 + ddr);
        lx[ttr][ddr + 0] = (float)xv[0];
        lx[ttr][ddr + 1] = (float)xv[1];
        lx[ttr][ddr + 2] = (float)xv[2];
        lx[ttr][ddr + 3] = (float)xv[3];
        if (tid < 64) {
            int tt2 = tid >> 2, ss = tid & 3;
            la[tt2][ss] = alpha[((size_t)b * Tt + t0base + t0 + tt2) * 64 + h * 4 + ss];
        }
        __syncthreads();
#pragma unroll
        for (int q = 0; q < 16; ++q) {
            float av = la[q][s];
            acc = fmaf(av, lx[q][d], acc);
            wacc += av;
        }
        __syncthreads();
    }
    part[(((size_t)c * 64 + bh) * 4 + s) * 64 + d] = acc;
    if (d == 0) partw[((size_t)c * 64 + bh) * 4 + s] = wacc;
}

__global__ __launch_bounds__(256) void pool_comb_k(const float* __restrict__ part,
                                                   const float* __restrict__ partw,
                                                   float* __restrict__ slot_in) {
    int bh = blockIdx.x;
    int tid = threadIdx.x;
    int s = tid >> 6, d = tid & 63;
    float acc = 0.f, w = 0.f;
    for (int c = 0; c < 8; ++c) {
        acc += part[(((size_t)c * 64 + bh) * 4 + s) * 64 + d];
        w   += partw[((size_t)c * 64 + bh) * 4 + s];
    }
    slot_in[((size_t)bh * 4 + s) * 64 + d] = acc / (w + 1e-8f);
}

// ---------------- K5: GRU + slot MLP ----------------
__global__ __launch_bounds__(64) void gru_k(const float* __restrict__ slot_in,
                                            const float* __restrict__ slot_init,
                                            const float* __restrict__ gwi,
                                            const float* __restrict__ gwh,
                                            const float* __restrict__ gbi,
                                            const float* __restrict__ gbh,
                                            const float* __restrict__ hpw,
                                            const float* __restrict__ hpb,
                                            const float* __restrict__ ohw,
                                            const float* __restrict__ ohb,
                                            float* __restrict__ S_new) {
    int slot = blockIdx.x;
    int hs = slot & 63;
    int d = threadIdx.x;
    __shared__ float si[64], hp[64], hn[64], g[256];
    si[d] = slot_in[(size_t)slot * 64 + d];
    hp[d] = slot_init[(size_t)hs * 64 + d];
    __syncthreads();
    float gi_r = gbi[d], gi_z = gbi[64 + d], gi_n = gbi[128 + d];
    float gh_r = gbh[d], gh_z = gbh[64 + d], gh_n = gbh[128 + d];
    for (int k = 0; k < 64; ++k) {
        float sv = si[k], hv = hp[k];
        gi_r = fmaf(sv, gwi[(size_t)(d) * 64 + k], gi_r);
        gi_z = fmaf(sv, gwi[(size_t)(64 + d) * 64 + k], gi_z);
        gi_n = fmaf(sv, gwi[(size_t)(128 + d) * 64 + k], gi_n);
        gh_r = fmaf(hv, gwh[(size_t)(d) * 64 + k], gh_r);
        gh_z = fmaf(hv, gwh[(size_t)(64 + d) * 64 + k], gh_z);
        gh_n = fmaf(hv, gwh[(size_t)(128 + d) * 64 + k], gh_n);
    }
    float r = 1.0f / (1.0f + expf(-(gi_r + gh_r)));
    float z = 1.0f / (1.0f + expf(-(gi_z + gh_z)));
    float n = tanhf(gi_n + r * gh_n);
    float hnew = (1.0f - z) * n + z * hp[d];
    hn[d] = hnew;
    __syncthreads();
    float p0 = hpb[d], p1 = hpb[64 + d], p2 = hpb[128 + d], p3 = hpb[192 + d];
    for (int k = 0; k < 64; ++k) {
        float hv = hn[k];
        p0 = fmaf(hv, hpw[(size_t)k * 256 + d], p0);
        p1 = fmaf(hv, hpw[(size_t)k * 256 + 64 + d], p1);
        p2 = fmaf(hv, hpw[(size_t)k * 256 + 128 + d], p2);
        p3 = fmaf(hv, hpw[(size_t)k * 256 + 192 + d], p3);
    }
    g[d] = gelu_f(p0); g[64 + d] = gelu_f(p1); g[128 + d] = gelu_f(p2); g[192 + d] = gelu_f(p3);
    __syncthreads();
    float o = ohb[d];
    for (int j = 0; j < 256; ++j) o = fmaf(g[j], ohw[(size_t)j * 64 + d], o);
    S_new[(size_t)slot * 64 + d] = o;
}

// ---------------- K6: PT[b][j][hs] = sum_d Snew[b,hs,d] * vpw[h*64+d, j]  (f16) -------
__global__ __launch_bounds__(256) void pmat_k(const float* __restrict__ Snew,
                                              const float* __restrict__ vpw,
                                              _Float16* __restrict__ PT) {
    const int h = blockIdx.y;
    const int tid = threadIdx.x;
    const int j = blockIdx.x * 256 + tid;
    __shared__ float S[16][64];
    for (int i = tid; i < 1024; i += 256) {
        int row = i >> 6, d = i & 63;
        int b = row >> 2, s = row & 3;
        S[row][d] = Snew[((size_t)b * 64 + h * 4 + s) * 64 + d];
    }
    __syncthreads();
    float acc[16];
#pragma unroll
    for (int r = 0; r < 16; ++r) acc[r] = 0.f;
    const float* wp = vpw + (size_t)h * 64 * HMm + j;
#pragma unroll 4
    for (int d = 0; d < 64; ++d) {
        float w = wp[(size_t)d * HMm];
#pragma unroll
        for (int r = 0; r < 16; ++r) acc[r] = fmaf(S[r][d], w, acc[r]);
    }
#pragma unroll
    for (int b = 0; b < 4; ++b) {
        f16x4 o;
#pragma unroll
        for (int s = 0; s < 4; ++s) o[s] = (_Float16)acc[b * 4 + s];
        *(f16x4*)&PT[((size_t)b * HMm + j) * 64 + h * 4] = o;
    }
}

// ---------------- K7: transpose + fp32->fp16 convert ----------------
__global__ __launch_bounds__(256) void transp_f16_k(const float* __restrict__ in,
                                                    _Float16* __restrict__ out,
                                                    int K, int N) {
    __shared__ float t[32][33];
    int n0 = blockIdx.x * 32, k0 = blockIdx.y * 32;
    int tx = threadIdx.x & 31, ty = threadIdx.x >> 5;
#pragma unroll
    for (int i = 0; i < 32; i += 8)
        t[ty + i][tx] = in[(size_t)(k0 + ty + i) * N + n0 + tx];
    __syncthreads();
#pragma unroll
    for (int i = 0; i < 32; i += 8)
        out[(size_t)(n0 + ty + i) * K + k0 + tx] = (_Float16)t[tx][ty + i];
}

// ---------------- K9: vgen = gelu(alpha16 @ PT[b]^T + vpb), single launch, K=64 -------
__global__ __launch_bounds__(256) void vgen_k(const _Float16* __restrict__ alpha16,
                                              const _Float16* __restrict__ PT,
                                              const float* __restrict__ vpb,
                                              _Float16* __restrict__ v1a,
                                              _Float16* __restrict__ v1b) {
    __shared__ __align__(16) _Float16 As[128][64];
    __shared__ __align__(16) _Float16 Bs[128][64];
    const int tid = threadIdx.x;
    const int wid = tid >> 6;
    const int lane = tid & 63;
    const int swz = xcd_swz(gridDim.x * gridDim.y);
    const int brow = (swz / gridDim.x) * 128;
    const int bcol = (swz % gridDim.x) * 128;
    const int b = brow >> 12;
    const _Float16* Bt = PT + (size_t)b * HMm * 64;
    _Float16* Cb = (brow < 8192) ? v1a : v1b;
    const int rowoff = (brow < 8192) ? brow : brow - 8192;
    const int wr = (wid >> 1) * 64;
    const int wc = (wid & 1) * 64;

    f32x4 acc[4][4];
#pragma unroll
    for (int m = 0; m < 4; ++m)
#pragma unroll
        for (int n = 0; n < 4; ++n)
            acc[m][n] = f32x4{0.f, 0.f, 0.f, 0.f};

    const int lrow = lane >> 3;
    const int lcol = (lane & 7) * 8;
    const int fr = lane & 15;
    const int fk = (lane >> 4) * 8;

#pragma unroll
    for (int i = 0; i < 4; ++i) {
        int seg = wid * 4 + i;
        const _Float16* g = alpha16 + (size_t)(brow + seg * 8 + lrow) * 64 + lcol;
        __builtin_amdgcn_global_load_lds(
            (const __attribute__((address_space(1))) void*)g,
            (__attribute__((address_space(3))) void*)&As[seg * 8][0], 16, 0, 0);
    }
#pragma unroll
    for (int i = 0; i < 4; ++i) {
        int seg = wid * 4 + i;
        const _Float16* g = Bt + (size_t)(bcol + seg * 8 + lrow) * 64 + lcol;
        __builtin_amdgcn_global_load_lds(
            (const __attribute__((address_space(1))) void*)g,
            (__attribute__((address_space(3))) void*)&Bs[seg * 8][0], 16, 0, 0);
    }
    __syncthreads();
#pragma unroll
    for (int kb = 0; kb < 2; ++kb) {
        f16x8 af[4], bf[4];
#pragma unroll
        for (int m = 0; m < 4; ++m)
            af[m] = *(const f16x8*)&As[wr + m * 16 + fr][kb * 32 + fk];
#pragma unroll
        for (int n = 0; n < 4; ++n)
            bf[n] = *(const f16x8*)&Bs[wc + n * 16 + fr][kb * 32 + fk];
#pragma unroll
        for (int m = 0; m < 4; ++m)
#pragma unroll
            for (int n = 0; n < 4; ++n)
                acc[m][n] = __builtin_amdgcn_mfma_f32_16x16x32_f16(af[m], bf[n], acc[m][n], 0, 0, 0);
    }

    const int crow = (lane >> 4) * 4;
#pragma unroll
    for (int m = 0; m < 4; ++m) {
        int row0 = rowoff + wr + m * 16 + crow;
#pragma unroll
        for (int n = 0; n < 4; ++n) {
            int col = bcol + wc + n * 16 + fr;
            float bv = vpb[col];
#pragma unroll
            for (int r = 0; r < 4; ++r) {
                float v = acc[m][n][r] + bv;
                Cb[(size_t)(row0 + r) * HMm + col] = (_Float16)gelu_f(v);
            }
        }
    }
}

// ---------------- K11: 256x256 GEMM, BK=64 ring-2, 4-phase (m201-class schedule) ------
template <int OUT_F16>
__global__ __launch_bounds__(512, 2) void hgemm8_k(const _Float16* __restrict__ A0,
                                                   const _Float16* __restrict__ A1,
                                                   int splitrow,
                                                   const _Float16* __restrict__ Bt,
                                                   const float* __restrict__ bias,
                                                   void* __restrict__ Cv,
                                                   int M, int N, int K) {
    __shared__ __align__(16) _Float16 As[2][256][64];   // 64 KB
    __shared__ __align__(16) _Float16 Bs[2][256][64];   // 64 KB
    const int tid = threadIdx.x;
    const int wid = tid >> 6;            // 0..7
    const int lane = tid & 63;
    const int swz = xcd_swz(gridDim.x * gridDim.y);
    const int brow = (swz / gridDim.x) * 256;
    const int bcol = (swz % gridDim.x) * 256;
    const _Float16* Ab = (brow < splitrow) ? A0 : A1;
    const int arow0 = brow - ((brow < splitrow) ? 0 : splitrow);
    const int wm = wid >> 2;             // 0..1 -> 128-row half
    const int wn = wid & 3;              // 0..3 -> 64-col quarter

    const int srow = lane >> 3;                        // 0..7
    const int scol = ((lane & 7) ^ (lane >> 3)) * 8;   // f16 elems
    const int fr = lane & 15;
    const int fk0 = (((lane >> 4) ^ (lane & 7))) * 8;
    const int fk1 = (((4 + (lane >> 4)) ^ (lane & 7))) * 8;
    const int crow = (lane >> 4) * 4;

    const int nk = K >> 6;

    f32x4 acc[8][4];
#pragma unroll
    for (int m = 0; m < 8; ++m)
#pragma unroll
        for (int n = 0; n < 4; ++n)
            acc[m][n] = f32x4{0.f, 0.f, 0.f, 0.f};

    auto stage = [&](int t) {
        const int slot = t & 1;
        const size_t kk = (size_t)t << 6;
#pragma unroll
        for (int j = 0; j < 4; ++j) {
            const _Float16* ga = Ab + (size_t)(arow0 + j * 64 + wid * 8 + srow) * K + kk + scol;
            __builtin_amdgcn_global_load_lds(
                (const __attribute__((address_space(1))) void*)ga,
                (__attribute__((address_space(3))) void*)&As[slot][j * 64 + wid * 8][0], 16, 0, 0);
        }
#pragma unroll
        for (int j = 0; j < 4; ++j) {
            const _Float16* gb = Bt + (size_t)(bcol + j * 64 + wid * 8 + srow) * K + kk + scol;
            __builtin_amdgcn_global_load_lds(
                (const __attribute__((address_space(1))) void*)gb,
                (__attribute__((address_space(3))) void*)&Bs[slot][j * 64 + wid * 8][0], 16, 0, 0);
        }
    };

    stage(0);
    stage(1);

    for (int t = 0; t < nk; ++t) {
        if (t + 1 < nk) asm volatile("s_waitcnt vmcnt(8)" ::: "memory");
        else            asm volatile("s_waitcnt vmcnt(0)" ::: "memory");
        __builtin_amdgcn_sched_barrier(0);
        __builtin_amdgcn_s_barrier();
        __builtin_amdgcn_sched_barrier(0);

        const int slot = t & 1;
        f16x8 af[4][2], bf[4][2];
#pragma unroll
        for (int m = 0; m < 4; ++m) {
            af[m][0] = *(const f16x8*)&As[slot][wm * 128 + m * 16 + fr][fk0];
            af[m][1] = *(const f16x8*)&As[slot][wm * 128 + m * 16 + fr][fk1];
        }
#pragma unroll
        for (int n = 0; n < 2; ++n) {
            bf[n][0] = *(const f16x8*)&Bs[slot][wn * 64 + n * 16 + fr][fk0];
            bf[n][1] = *(const f16x8*)&Bs[slot][wn * 64 + n * 16 + fr][fk1];
        }
        __builtin_amdgcn_sched_barrier(0);
        __builtin_amdgcn_s_barrier();
        asm volatile("s_waitcnt lgkmcnt(0)" ::: "memory");
        __builtin_amdgcn_sched_barrier(0);
        __builtin_amdgcn_s_setprio(1);
#pragma unroll
        for (int m = 0; m < 4; ++m)
#pragma unroll
            for (int n = 0; n < 2; ++n)
#pragma unroll
                for (int kk = 0; kk < 2; ++kk)
                    acc[m][n] = __builtin_amdgcn_mfma_f32_16x16x32_f16(af[m][kk], bf[n][kk], acc[m][n], 0, 0, 0);
        __builtin_amdgcn_s_setprio(0);
        __builtin_amdgcn_sched_barrier(0);
#pragma unroll
        for (int n = 2; n < 4; ++n) {
            bf[n][0] = *(const f16x8*)&Bs[slot][wn * 64 + n * 16 + fr][fk0];
            bf[n][1] = *(const f16x8*)&Bs[slot][wn * 64 + n * 16 + fr][fk1];
        }
        __builtin_amdgcn_sched_barrier(0);
        __builtin_amdgcn_s_barrier();
        asm volatile("s_waitcnt lgkmcnt(0)" ::: "memory");
        __builtin_amdgcn_sched_barrier(0);
        __builtin_amdgcn_s_setprio(1);
#pragma unroll
        for (int m = 0; m < 4; ++m)
#pragma unroll
            for (int n = 2; n < 4; ++n)
#pragma unroll
                for (int kk = 0; kk < 2; ++kk)
                    acc[m][n] = __builtin_amdgcn_mfma_f32_16x16x32_f16(af[m][kk], bf[n][kk], acc[m][n], 0, 0, 0);
        __builtin_amdgcn_s_setprio(0);
        __builtin_amdgcn_sched_barrier(0);
#pragma unroll
        for (int m = 0; m < 4; ++m) {
            af[m][0] = *(const f16x8*)&As[slot][wm * 128 + (m + 4) * 16 + fr][fk0];
            af[m][1] = *(const f16x8*)&As[slot][wm * 128 + (m + 4) * 16 + fr][fk1];
        }
        __builtin_amdgcn_sched_barrier(0);
        __builtin_amdgcn_s_barrier();
        asm volatile("s_waitcnt lgkmcnt(0)" ::: "memory");
        __builtin_amdgcn_sched_barrier(0);
        __builtin_amdgcn_s_setprio(1);
#pragma unroll
        for (int m = 0; m < 4; ++m)
#pragma unroll
            for (int n = 0; n < 2; ++n)
#pragma unroll
                for (int kk = 0; kk < 2; ++kk)
                    acc[m + 4][n] = __builtin_amdgcn_mfma_f32_16x16x32_f16(af[m][kk], bf[n][kk], acc[m + 4][n], 0, 0, 0);
        __builtin_amdgcn_s_setprio(0);
        __builtin_amdgcn_sched_barrier(0);
        __builtin_amdgcn_s_barrier();
        __builtin_amdgcn_sched_barrier(0);
        if (t + 2 < nk) stage(t + 2);
        __builtin_amdgcn_s_setprio(1);
#pragma unroll
        for (int m = 0; m < 4; ++m)
#pragma unroll
            for (int n = 2; n < 4; ++n)
#pragma unroll
                for (int kk = 0; kk < 2; ++kk)
                    acc[m + 4][n] = __builtin_amdgcn_mfma_f32_16x16x32_f16(af[m][kk], bf[n][kk], acc[m + 4][n], 0, 0, 0);
        __builtin_amdgcn_s_setprio(0);
        __builtin_amdgcn_sched_barrier(0);
    }

#pragma unroll
    for (int m = 0; m < 8; ++m) {
        int row0 = brow + wm * 128 + m * 16 + crow;
#pragma unroll
        for (int n = 0; n < 4; ++n) {
            int col = bcol + wn * 64 + n * 16 + fr;
            float bv = bias[col];
#pragma unroll
            for (int r = 0; r < 4; ++r) {
                float v = acc[m][n][r] + bv;
                size_t idx = (size_t)(row0 + r) * N + col;
                if (OUT_F16) ((_Float16*)Cv)[idx] = (_Float16)v;
                else ((float*)Cv)[idx] = v;
            }
        }
    }
    (void)M;
}

extern "C" void kernel_launch(void* const* d_in, const int* in_sizes, int n_in,
                              void* d_out, int out_size, void* d_ws, size_t ws_size,
                              hipStream_t stream) {
    const float* x         = (const float*)d_in[0];
    const float* slot_init = (const float*)d_in[1];
    const float* rw1       = (const float*)d_in[2];
    const float* rb1       = (const float*)d_in[3];
    const float* rw2       = (const float*)d_in[4];
    const float* rb2       = (const float*)d_in[5];
    const float* gwi       = (const float*)d_in[6];
    const float* gwh       = (const float*)d_in[7];
    const float* gbi       = (const float*)d_in[8];
    const float* gbh       = (const float*)d_in[9];
    const float* hpw       = (const float*)d_in[10];
    const float* hpb       = (const float*)d_in[11];
    const float* ohw       = (const float*)d_in[12];
    const float* ohb       = (const float*)d_in[13];
    const float* vpw       = (const float*)d_in[14];
    const float* vpb       = (const float*)d_in[15];
    const float* vow       = (const float*)d_in[16];
    const float* vob       = (const float*)d_in[17];
    const float* opw       = (const float*)d_in[18];
    const float* opb       = (const float*)d_in[19];
    const float* tau       = (const float*)d_in[20];
    float* out = (float*)d_out;

    float* ws = (float*)d_ws;
    size_t off = 0;
    auto alloc = [&](size_t nfloats) { float* p = ws + off; off += (nfloats + 63) & ~(size_t)63; return p; };

    float* cb     = alloc(1024);
    float* cbp    = alloc(16 * 1024);
    float* h1     = alloc((size_t)MTOK * 1024);            // fp32; dead after logtop:
    _Float16* v1a = (_Float16*)h1;                          //   v1 rows 0..8191 [8192,4096] f16
    float* alpha  = alloc((size_t)MTOK * 64);
    _Float16* alpha16 = (_Float16*)alloc((size_t)MTOK * 64 / 2);
    float* slotin = alloc(256 * 64);
    float* part   = alloc((size_t)8 * 64 * 4 * 64);
    float* partw  = alloc(8 * 64 * 4);
    float* Snew   = alloc(256 * 64);
    _Float16* PT   = (_Float16*)alloc((size_t)Bb * HMm * 64 / 2);  // [4,4096,64] f16
    _Float16* vowT = (_Float16*)alloc((size_t)Dd * HMm / 2);       // [1024,4096] f16
    _Float16* opwT = (_Float16*)alloc((size_t)Dd * Dd / 2);        // [1024,1024] f16
    _Float16* v2f16 = (_Float16*)alloc((size_t)MTOK * Dd / 2);     // [16384,1024] f16
    _Float16* w1hiT = (_Float16*)alloc((size_t)Dd * Dd / 2);
    _Float16* w1loT = (_Float16*)alloc((size_t)Dd * Dd / 2);

    // d_out scratch: xhi/xlo before hgemm4p (xhi also read by pool); v1b after vgen.
    _Float16* xhi = (_Float16*)d_out;
    _Float16* xlo = xhi + (size_t)MTOK * Dd;
    _Float16* v1b = (_Float16*)d_out;

    // ---- routing: pre-split x + deep-pipelined 4-plane split-fp16 GEMM + fused logtop --
    cb_part_k<<<dim3(4, 16), 256, 0, stream>>>(slot_init, rw1, cbp);
    cb_comb_k<<<4, 256, 0, stream>>>(cbp, cb);
    wsplitT_k<<<dim3(Dd / 32, Dd / 32), 256, 0, stream>>>(rw1, w1hiT, w1loT);
    xsplit_k<<<(MTOK * Dd) / (256 * 8), 256, 0, stream>>>(x, xhi, xlo);
    hgemm4p_k<<<dim3(Dd / 256, MTOK / 256), 512, 0, stream>>>(
        xhi, xlo, w1hiT, w1loT, rb1, cb, h1, MTOK, Dd, Dd);
    logtop_k<<<MTOK / 64, 256, 0, stream>>>(h1, rw2, rb2, tau, alpha, alpha16);

    // ---- weight transposes (fp32 -> fp16 [N,K]) ----
    transp_f16_k<<<dim3(Dd / 32, HMm / 32), 256, 0, stream>>>(vow, vowT, HMm, Dd);
    transp_f16_k<<<dim3(Dd / 32, Dd / 32), 256, 0, stream>>>(opw, opwT, Dd, Dd);

    // ---- slot pooling (f16 x) + GRU + slot MLP ----
    pool_part_k<<<dim3(64, 8), 256, 0, stream>>>(xhi, alpha, part, partw);
    pool_comb_k<<<64, 256, 0, stream>>>(part, partw, slotin);
    gru_k<<<256, 64, 0, stream>>>(slotin, slot_init, gwi, gwh, gbi, gbh,
                                  hpw, hpb, ohw, ohb, Snew);

    // ---- P[b] = S_emb[b] @ vpw (stored transposed f16 [b][j][hs]) ----
    pmat_k<<<dim3(HMm / 256, Hh), 256, 0, stream>>>(Snew, vpw, PT);

    // ---- value MLP: vgen (K=64), then BK=64 4-phase 256^2 GEMM2 + GEMM3 ----
    vgen_k<<<dim3(HMm / 128, MTOK / 128), 256, 0, stream>>>(
        alpha16, PT, vpb, v1a, v1b);
    hgemm8_k<1><<<dim3(Dd / 256, MTOK / 256), 512, 0, stream>>>(
        v1a, v1b, 8192, vowT, vob, v2f16, MTOK, Dd, HMm);
    hgemm8_k<0><<<dim3(Dd / 256, MTOK / 256), 512, 0, stream>>>(
        v2f16, v2f16, MTOK, opwT, opb, out, MTOK, Dd, Dd);

    (void)in_sizes; (void)n_in; (void)out_size; (void)ws_size;
}

// Round 14
// 487.238 us; speedup vs baseline: 1.0829x; 1.0829x over previous
//
#include <hip/hip_runtime.h>
#include <cstddef>
#include <cstdint>

// Problem constants
#define Bb 4
#define Tt 4096
#define Dd 1024
#define Hh 16
#define HDd 64
#define NSs 64
#define SPHh 4
#define HMm 4096
#define MTOK (Bb*Tt)   // 16384

typedef _Float16 f16x8 __attribute__((ext_vector_type(8)));
typedef _Float16 f16x4 __attribute__((ext_vector_type(4)));
typedef float f32x4 __attribute__((ext_vector_type(4)));

__device__ __forceinline__ float gelu_f(float x) {
    return 0.5f * x * (1.0f + erff(x * 0.70710678118654752440f));
}

// XCD-chunked bijective block swizzle (requires nwg % 8 == 0; all launches comply)
__device__ __forceinline__ int xcd_swz(int nwg) {
    int orig = blockIdx.y * gridDim.x + blockIdx.x;
    int cpx = nwg >> 3;
    return (orig & 7) * cpx + (orig >> 3);
}

// ---------------- K0: cb partials ----------------
__global__ __launch_bounds__(256) void cb_part_k(const float* __restrict__ slot_init,
                                                 const float* __restrict__ rw1,
                                                 float* __restrict__ cbp) {
    __shared__ float sm[64];
    int tid = threadIdx.x;
    if (tid < 64) {
        float s = 0.f;
        for (int i = 0; i < 64; ++i) s += slot_init[i * 64 + tid];
        sm[tid] = s * (1.0f / 64.0f);
    }
    __syncthreads();
    int j = blockIdx.x * 256 + tid;
    int k0 = blockIdx.y * 64;
    float acc = 0.f;
#pragma unroll 8
    for (int k = 0; k < 64; ++k)
        acc = fmaf(sm[k], rw1[(size_t)(1024 + k0 + k) * 1024 + j], acc);
    cbp[(size_t)blockIdx.y * 1024 + j] = acc;
}

__global__ __launch_bounds__(256) void cb_comb_k(const float* __restrict__ cbp,
                                                 float* __restrict__ cb) {
    int j = blockIdx.x * 256 + threadIdx.x;
    float acc = 0.f;
#pragma unroll
    for (int c = 0; c < 16; ++c) acc += cbp[(size_t)c * 1024 + j];
    cb[j] = acc;
}

// ---------------- K1: rw1[:1024] -> transposed split-f16 planes ----------------
__global__ __launch_bounds__(256) void wsplitT_k(const float* __restrict__ rw1,
                                                 _Float16* __restrict__ whiT,
                                                 _Float16* __restrict__ wloT) {
    __shared__ float t[32][33];
    int n0 = blockIdx.x * 32, k0 = blockIdx.y * 32;
    int tx = threadIdx.x & 31, ty = threadIdx.x >> 5;
#pragma unroll
    for (int i = 0; i < 32; i += 8)
        t[ty + i][tx] = rw1[(size_t)(k0 + ty + i) * 1024 + n0 + tx];
    __syncthreads();
#pragma unroll
    for (int i = 0; i < 32; i += 8) {
        float v = t[tx][ty + i];
        _Float16 h = (_Float16)v;
        _Float16 l = (_Float16)(v - (float)h);
        whiT[(size_t)(n0 + ty + i) * 1024 + k0 + tx] = h;
        wloT[(size_t)(n0 + ty + i) * 1024 + k0 + tx] = l;
    }
}

// ---------------- K1a: x -> split f16 hi/lo planes ----------------
__global__ __launch_bounds__(256) void xsplit_k(const float* __restrict__ x,
                                                _Float16* __restrict__ xhi,
                                                _Float16* __restrict__ xlo) {
    size_t i = ((size_t)blockIdx.x * 256 + threadIdx.x) * 8;
    float4 a = *(const float4*)(x + i);
    float4 b = *(const float4*)(x + i + 4);
    float v[8] = {a.x, a.y, a.z, a.w, b.x, b.y, b.z, b.w};
    f16x8 h, l;
#pragma unroll
    for (int j = 0; j < 8; ++j) {
        _Float16 hv = (_Float16)v[j];
        h[j] = hv;
        l[j] = (_Float16)(v[j] - (float)hv);
    }
    *(f16x8*)(xhi + i) = h;
    *(f16x8*)(xlo + i) = l;
}

// ---------------- K1b: deep-pipelined split-fp16 routing GEMM ----------------
// 256x256 tile, BK=32, ring-2, counted vmcnt, 4-phase (hgemm8-mirror skeleton).
__global__ __launch_bounds__(512, 2) void hgemm4p_k(const _Float16* __restrict__ Ah,
                                                    const _Float16* __restrict__ Al,
                                                    const _Float16* __restrict__ Bh,
                                                    const _Float16* __restrict__ Bl,
                                                    const float* __restrict__ bias1,
                                                    const float* __restrict__ bias2,
                                                    float* __restrict__ C,
                                                    int M, int N, int K) {
    __shared__ __align__(16) _Float16 Ahs[2][256][32];
    __shared__ __align__(16) _Float16 Als[2][256][32];
    __shared__ __align__(16) _Float16 Bhs[2][256][32];
    __shared__ __align__(16) _Float16 Bls[2][256][32];
    const int tid = threadIdx.x;
    const int wid = tid >> 6;            // 0..7
    const int lane = tid & 63;
    const int swz = xcd_swz(gridDim.x * gridDim.y);
    const int brow = (swz / gridDim.x) * 256;
    const int bcol = (swz % gridDim.x) * 256;
    const int wm = wid >> 2;             // 0..1
    const int wn = wid & 3;              // 0..3

    const int srow = lane >> 2;
    const int scol = ((lane & 3) ^ ((lane >> 3) & 3)) * 8;
    const int fr = lane & 15;
    const int fkp = (((lane >> 4) ^ ((lane >> 1) & 3))) * 8;
    const int crow = (lane >> 4) * 4;

    const int nk = K >> 5;   // 32

    f32x4 acc[8][4];
#pragma unroll
    for (int m = 0; m < 8; ++m)
#pragma unroll
        for (int n = 0; n < 4; ++n)
            acc[m][n] = f32x4{0.f, 0.f, 0.f, 0.f};

    auto stage = [&](int t) {
        const int slot = t & 1;
        const size_t kk = (size_t)t << 5;
#pragma unroll
        for (int i = 0; i < 2; ++i) {
            int r0 = wid * 32 + i * 16;
            const _Float16* gah = Ah + (size_t)(brow + r0 + srow) * K + kk + scol;
            __builtin_amdgcn_global_load_lds(
                (const __attribute__((address_space(1))) void*)gah,
                (__attribute__((address_space(3))) void*)&Ahs[slot][r0][0], 16, 0, 0);
            const _Float16* gal = Al + (size_t)(brow + r0 + srow) * K + kk + scol;
            __builtin_amdgcn_global_load_lds(
                (const __attribute__((address_space(1))) void*)gal,
                (__attribute__((address_space(3))) void*)&Als[slot][r0][0], 16, 0, 0);
            const _Float16* gbh = Bh + (size_t)(bcol + r0 + srow) * K + kk + scol;
            __builtin_amdgcn_global_load_lds(
                (const __attribute__((address_space(1))) void*)gbh,
                (__attribute__((address_space(3))) void*)&Bhs[slot][r0][0], 16, 0, 0);
            const _Float16* gbl = Bl + (size_t)(bcol + r0 + srow) * K + kk + scol;
            __builtin_amdgcn_global_load_lds(
                (const __attribute__((address_space(1))) void*)gbl,
                (__attribute__((address_space(3))) void*)&Bls[slot][r0][0], 16, 0, 0);
        }
    };

    stage(0);
    if (nk > 1) stage(1);

    for (int t = 0; t < nk; ++t) {
        if (t + 1 < nk) asm volatile("s_waitcnt vmcnt(8)" ::: "memory");
        else            asm volatile("s_waitcnt vmcnt(0)" ::: "memory");
        __builtin_amdgcn_sched_barrier(0);
        __builtin_amdgcn_s_barrier();     // tile t staged by all waves
        __builtin_amdgcn_sched_barrier(0);

        const int slot = t & 1;
        f16x8 afh[4], afl[4], bfh[4], bfl[4];
        // ---- p0: A m0-3 (hi/lo) + B n0-1 (hi/lo); MFMA m0-3 x n0-1 ----
#pragma unroll
        for (int m = 0; m < 4; ++m) {
            afh[m] = *(const f16x8*)&Ahs[slot][wm * 128 + m * 16 + fr][fkp];
            afl[m] = *(const f16x8*)&Als[slot][wm * 128 + m * 16 + fr][fkp];
        }
#pragma unroll
        for (int n = 0; n < 2; ++n) {
            bfh[n] = *(const f16x8*)&Bhs[slot][wn * 64 + n * 16 + fr][fkp];
            bfl[n] = *(const f16x8*)&Bls[slot][wn * 64 + n * 16 + fr][fkp];
        }
        __builtin_amdgcn_sched_barrier(0);
        __builtin_amdgcn_s_barrier();
        asm volatile("s_waitcnt lgkmcnt(0)" ::: "memory");
        __builtin_amdgcn_sched_barrier(0);
        __builtin_amdgcn_s_setprio(1);
#pragma unroll
        for (int m = 0; m < 4; ++m)
#pragma unroll
            for (int n = 0; n < 2; ++n) {
                acc[m][n] = __builtin_amdgcn_mfma_f32_16x16x32_f16(afl[m], bfh[n], acc[m][n], 0, 0, 0);
                acc[m][n] = __builtin_amdgcn_mfma_f32_16x16x32_f16(afh[m], bfl[n], acc[m][n], 0, 0, 0);
                acc[m][n] = __builtin_amdgcn_mfma_f32_16x16x32_f16(afh[m], bfh[n], acc[m][n], 0, 0, 0);
            }
        __builtin_amdgcn_s_setprio(0);
        __builtin_amdgcn_sched_barrier(0);
        // ---- p1: B n2-3; MFMA m0-3 x n2-3 ----
#pragma unroll
        for (int n = 2; n < 4; ++n) {
            bfh[n] = *(const f16x8*)&Bhs[slot][wn * 64 + n * 16 + fr][fkp];
            bfl[n] = *(const f16x8*)&Bls[slot][wn * 64 + n * 16 + fr][fkp];
        }
        __builtin_amdgcn_sched_barrier(0);
        __builtin_amdgcn_s_barrier();
        asm volatile("s_waitcnt lgkmcnt(0)" ::: "memory");
        __builtin_amdgcn_sched_barrier(0);
        __builtin_amdgcn_s_setprio(1);
#pragma unroll
        for (int m = 0; m < 4; ++m)
#pragma unroll
            for (int n = 2; n < 4; ++n) {
                acc[m][n] = __builtin_amdgcn_mfma_f32_16x16x32_f16(afl[m], bfh[n], acc[m][n], 0, 0, 0);
                acc[m][n] = __builtin_amdgcn_mfma_f32_16x16x32_f16(afh[m], bfl[n], acc[m][n], 0, 0, 0);
                acc[m][n] = __builtin_amdgcn_mfma_f32_16x16x32_f16(afh[m], bfh[n], acc[m][n], 0, 0, 0);
            }
        __builtin_amdgcn_s_setprio(0);
        __builtin_amdgcn_sched_barrier(0);
        // ---- p2: A m4-7 (reuse regs); MFMA m4-7 x n0-1 ----
#pragma unroll
        for (int m = 0; m < 4; ++m) {
            afh[m] = *(const f16x8*)&Ahs[slot][wm * 128 + (m + 4) * 16 + fr][fkp];
            afl[m] = *(const f16x8*)&Als[slot][wm * 128 + (m + 4) * 16 + fr][fkp];
        }
        __builtin_amdgcn_sched_barrier(0);
        __builtin_amdgcn_s_barrier();
        asm volatile("s_waitcnt lgkmcnt(0)" ::: "memory");
        __builtin_amdgcn_sched_barrier(0);
        __builtin_amdgcn_s_setprio(1);
#pragma unroll
        for (int m = 0; m < 4; ++m)
#pragma unroll
            for (int n = 0; n < 2; ++n) {
                acc[m + 4][n] = __builtin_amdgcn_mfma_f32_16x16x32_f16(afl[m], bfh[n], acc[m + 4][n], 0, 0, 0);
                acc[m + 4][n] = __builtin_amdgcn_mfma_f32_16x16x32_f16(afh[m], bfl[n], acc[m + 4][n], 0, 0, 0);
                acc[m + 4][n] = __builtin_amdgcn_mfma_f32_16x16x32_f16(afh[m], bfh[n], acc[m + 4][n], 0, 0, 0);
            }
        __builtin_amdgcn_s_setprio(0);
        __builtin_amdgcn_sched_barrier(0);
        // slot fully read by ALL waves past this barrier -> safe to overwrite
        __builtin_amdgcn_s_barrier();
        __builtin_amdgcn_sched_barrier(0);
        // ---- p3: stage t+2 (ring-2), MFMA m4-7 x n2-3 (reg-only) ----
        if (t + 2 < nk) stage(t + 2);
        __builtin_amdgcn_s_setprio(1);
#pragma unroll
        for (int m = 0; m < 4; ++m)
#pragma unroll
            for (int n = 2; n < 4; ++n) {
                acc[m + 4][n] = __builtin_amdgcn_mfma_f32_16x16x32_f16(afl[m], bfh[n], acc[m + 4][n], 0, 0, 0);
                acc[m + 4][n] = __builtin_amdgcn_mfma_f32_16x16x32_f16(afh[m], bfl[n], acc[m + 4][n], 0, 0, 0);
                acc[m + 4][n] = __builtin_amdgcn_mfma_f32_16x16x32_f16(afh[m], bfh[n], acc[m + 4][n], 0, 0, 0);
            }
        __builtin_amdgcn_s_setprio(0);
        __builtin_amdgcn_sched_barrier(0);
    }

#pragma unroll
    for (int m = 0; m < 8; ++m) {
        int row0 = brow + wm * 128 + m * 16 + crow;
#pragma unroll
        for (int n = 0; n < 4; ++n) {
            int col = bcol + wn * 64 + n * 16 + fr;
            float bv = bias1[col] + bias2[col];
#pragma unroll
            for (int r = 0; r < 4; ++r) {
                float v = acc[m][n][r] + bv;
                C[(size_t)(row0 + r) * N + col] = gelu_f(v);
            }
        }
    }
    (void)M;
}

// ---------------- K2: route logits (fp32, register-prefetch; bit-identical k-order) ---
__global__ __launch_bounds__(256) void logits2_k(const float* __restrict__ A,
                                                 const float* __restrict__ Bw,
                                                 const float* __restrict__ rb2,
                                                 const float* __restrict__ taup,
                                                 float* __restrict__ Cl) {
    __shared__ float At[16][68];
    __shared__ float Bs[16][64];
    const int tid = threadIdx.x;
    const int m0 = blockIdx.x * 64;
    const int rg = tid >> 4;
    const int cg = tid & 15;
    const int srow = tid >> 2;
    const int skk  = (tid & 3) * 4;
    const int bk = tid >> 4;
    const int bc = (tid & 15) * 4;

    float acc[4][4] = {};

    float4 av = *(const float4*)(A + (size_t)(m0 + srow) * 1024 + skk);
    float4 bv = *(const float4*)(Bw + (size_t)bk * 64 + bc);

    for (int k0 = 0; k0 < 1024; k0 += 16) {
        __syncthreads();
        At[skk + 0][srow] = av.x;
        At[skk + 1][srow] = av.y;
        At[skk + 2][srow] = av.z;
        At[skk + 3][srow] = av.w;
        *(float4*)&Bs[bk][bc] = bv;
        __syncthreads();
        if (k0 + 16 < 1024) {
            av = *(const float4*)(A + (size_t)(m0 + srow) * 1024 + k0 + 16 + skk);
            bv = *(const float4*)(Bw + (size_t)(k0 + 16 + bk) * 64 + bc);
        }
#pragma unroll
        for (int k = 0; k < 16; ++k) {
            float4 a4 = *(const float4*)&At[k][rg * 4];
            float4 b4 = *(const float4*)&Bs[k][cg * 4];
            float a[4] = {a4.x, a4.y, a4.z, a4.w};
            float b[4] = {b4.x, b4.y, b4.z, b4.w};
#pragma unroll
            for (int i = 0; i < 4; ++i)
#pragma unroll
                for (int j = 0; j < 4; ++j)
                    acc[i][j] = fmaf(a[i], b[j], acc[i][j]);
        }
    }
    float inv = 1.0f / (fabsf(taup[0]) + 0.1f);
#pragma unroll
    for (int i = 0; i < 4; ++i)
#pragma unroll
        for (int j = 0; j < 4; ++j)
            Cl[(size_t)(m0 + rg * 4 + i) * 64 + cg * 4 + j] =
                (acc[i][j] + rb2[cg * 4 + j]) * inv;
}

// ---------------- K3: top-32-of-64 + softmax -> dense alpha ----------------
__global__ __launch_bounds__(256) void topk_k(const float* __restrict__ logits,
                                              float* __restrict__ alpha,
                                              _Float16* __restrict__ alpha16) {
    int wave = threadIdx.x >> 6;
    int lane = threadIdx.x & 63;
    int t = blockIdx.x * 4 + wave;
    float li = logits[(size_t)t * 64 + lane];
    float m = li;
#pragma unroll
    for (int off = 32; off; off >>= 1) m = fmaxf(m, __shfl_xor(m, off, 64));
    int cnt = 0;
    for (int off = 1; off < 64; ++off) {
        int j = (lane + off) & 63;
        float lj = __shfl(li, j, 64);
        cnt += (lj > li) || (lj == li && j < lane);
    }
    float e = (cnt < 32) ? expf(li - m) : 0.0f;
    float s = e;
#pragma unroll
    for (int off = 32; off; off >>= 1) s += __shfl_xor(s, off, 64);
    float a = e / s;
    alpha[(size_t)t * 64 + lane] = a;
    alpha16[(size_t)t * 64 + lane] = (_Float16)a;
}

// ---------------- K4: slot pooling (reads f16 xhi; value-path tolerance) --------------
__global__ __launch_bounds__(256) void pool_part_k(const _Float16* __restrict__ xh,
                                                   const float* __restrict__ alpha,
                                                   float* __restrict__ part,
                                                   float* __restrict__ partw) {
    int bh = blockIdx.x;
    int c = blockIdx.y;
    int b = bh >> 4, h = bh & 15;
    int tid = threadIdx.x;
    int s = tid >> 6, d = tid & 63;
    __shared__ float lx[16][64];
    __shared__ float la[16][4];
    float acc = 0.f, wacc = 0.f;
    const int tchunk = Tt / 8;
    const int t0base = c * tchunk;
    for (int t0 = 0; t0 < tchunk; t0 += 16) {
        int ttr = tid >> 4;
        int ddr = (tid & 15) * 4;
        size_t trow = (size_t)b * Tt + t0base + t0 + ttr;
        f16x4 xv = *(const f16x4*)(xh + trow * Dd + h * 64 + ddr);
        lx[ttr][ddr + 0] = (float)xv[0];
        lx[ttr][ddr + 1] = (float)xv[1];
        lx[ttr][ddr + 2] = (float)xv[2];
        lx[ttr][ddr + 3] = (float)xv[3];
        if (tid < 64) {
            int tt2 = tid >> 2, ss = tid & 3;
            la[tt2][ss] = alpha[((size_t)b * Tt + t0base + t0 + tt2) * 64 + h * 4 + ss];
        }
        __syncthreads();
#pragma unroll
        for (int q = 0; q < 16; ++q) {
            float av = la[q][s];
            acc = fmaf(av, lx[q][d], acc);
            wacc += av;
        }
        __syncthreads();
    }
    part[(((size_t)c * 64 + bh) * 4 + s) * 64 + d] = acc;
    if (d == 0) partw[((size_t)c * 64 + bh) * 4 + s] = wacc;
}

__global__ __launch_bounds__(256) void pool_comb_k(const float* __restrict__ part,
                                                   const float* __restrict__ partw,
                                                   float* __restrict__ slot_in) {
    int bh = blockIdx.x;
    int tid = threadIdx.x;
    int s = tid >> 6, d = tid & 63;
    float acc = 0.f, w = 0.f;
    for (int c = 0; c < 8; ++c) {
        acc += part[(((size_t)c * 64 + bh) * 4 + s) * 64 + d];
        w   += partw[((size_t)c * 64 + bh) * 4 + s];
    }
    slot_in[((size_t)bh * 4 + s) * 64 + d] = acc / (w + 1e-8f);
}

// ---------------- K5: GRU + slot MLP ----------------
__global__ __launch_bounds__(64) void gru_k(const float* __restrict__ slot_in,
                                            const float* __restrict__ slot_init,
                                            const float* __restrict__ gwi,
                                            const float* __restrict__ gwh,
                                            const float* __restrict__ gbi,
                                            const float* __restrict__ gbh,
                                            const float* __restrict__ hpw,
                                            const float* __restrict__ hpb,
                                            const float* __restrict__ ohw,
                                            const float* __restrict__ ohb,
                                            float* __restrict__ S_new) {
    int slot = blockIdx.x;
    int hs = slot & 63;
    int d = threadIdx.x;
    __shared__ float si[64], hp[64], hn[64], g[256];
    si[d] = slot_in[(size_t)slot * 64 + d];
    hp[d] = slot_init[(size_t)hs * 64 + d];
    __syncthreads();
    float gi_r = gbi[d], gi_z = gbi[64 + d], gi_n = gbi[128 + d];
    float gh_r = gbh[d], gh_z = gbh[64 + d], gh_n = gbh[128 + d];
    for (int k = 0; k < 64; ++k) {
        float sv = si[k], hv = hp[k];
        gi_r = fmaf(sv, gwi[(size_t)(d) * 64 + k], gi_r);
        gi_z = fmaf(sv, gwi[(size_t)(64 + d) * 64 + k], gi_z);
        gi_n = fmaf(sv, gwi[(size_t)(128 + d) * 64 + k], gi_n);
        gh_r = fmaf(hv, gwh[(size_t)(d) * 64 + k], gh_r);
        gh_z = fmaf(hv, gwh[(size_t)(64 + d) * 64 + k], gh_z);
        gh_n = fmaf(hv, gwh[(size_t)(128 + d) * 64 + k], gh_n);
    }
    float r = 1.0f / (1.0f + expf(-(gi_r + gh_r)));
    float z = 1.0f / (1.0f + expf(-(gi_z + gh_z)));
    float n = tanhf(gi_n + r * gh_n);
    float hnew = (1.0f - z) * n + z * hp[d];
    hn[d] = hnew;
    __syncthreads();
    float p0 = hpb[d], p1 = hpb[64 + d], p2 = hpb[128 + d], p3 = hpb[192 + d];
    for (int k = 0; k < 64; ++k) {
        float hv = hn[k];
        p0 = fmaf(hv, hpw[(size_t)k * 256 + d], p0);
        p1 = fmaf(hv, hpw[(size_t)k * 256 + 64 + d], p1);
        p2 = fmaf(hv, hpw[(size_t)k * 256 + 128 + d], p2);
        p3 = fmaf(hv, hpw[(size_t)k * 256 + 192 + d], p3);
    }
    g[d] = gelu_f(p0); g[64 + d] = gelu_f(p1); g[128 + d] = gelu_f(p2); g[192 + d] = gelu_f(p3);
    __syncthreads();
    float o = ohb[d];
    for (int j = 0; j < 256; ++j) o = fmaf(g[j], ohw[(size_t)j * 64 + d], o);
    S_new[(size_t)slot * 64 + d] = o;
}

// ---------------- K6: PT[b][j][hs] = sum_d Snew[b,hs,d] * vpw[h*64+d, j]  (f16) -------
__global__ __launch_bounds__(256) void pmat_k(const float* __restrict__ Snew,
                                              const float* __restrict__ vpw,
                                              _Float16* __restrict__ PT) {
    const int h = blockIdx.y;
    const int tid = threadIdx.x;
    const int j = blockIdx.x * 256 + tid;
    __shared__ float S[16][64];
    for (int i = tid; i < 1024; i += 256) {
        int row = i >> 6, d = i & 63;
        int b = row >> 2, s = row & 3;
        S[row][d] = Snew[((size_t)b * 64 + h * 4 + s) * 64 + d];
    }
    __syncthreads();
    float acc[16];
#pragma unroll
    for (int r = 0; r < 16; ++r) acc[r] = 0.f;
    const float* wp = vpw + (size_t)h * 64 * HMm + j;
#pragma unroll 4
    for (int d = 0; d < 64; ++d) {
        float w = wp[(size_t)d * HMm];
#pragma unroll
        for (int r = 0; r < 16; ++r) acc[r] = fmaf(S[r][d], w, acc[r]);
    }
#pragma unroll
    for (int b = 0; b < 4; ++b) {
        f16x4 o;
#pragma unroll
        for (int s = 0; s < 4; ++s) o[s] = (_Float16)acc[b * 4 + s];
        *(f16x4*)&PT[((size_t)b * HMm + j) * 64 + h * 4] = o;
    }
}

// ---------------- K7: transpose + fp32->fp16 convert ----------------
__global__ __launch_bounds__(256) void transp_f16_k(const float* __restrict__ in,
                                                    _Float16* __restrict__ out,
                                                    int K, int N) {
    __shared__ float t[32][33];
    int n0 = blockIdx.x * 32, k0 = blockIdx.y * 32;
    int tx = threadIdx.x & 31, ty = threadIdx.x >> 5;
#pragma unroll
    for (int i = 0; i < 32; i += 8)
        t[ty + i][tx] = in[(size_t)(k0 + ty + i) * N + n0 + tx];
    __syncthreads();
#pragma unroll
    for (int i = 0; i < 32; i += 8)
        out[(size_t)(n0 + ty + i) * K + k0 + tx] = (_Float16)t[tx][ty + i];
}

// ---------------- K9: vgen = gelu(alpha16 @ PT[b]^T + vpb), single launch, K=64 -------
__global__ __launch_bounds__(256) void vgen_k(const _Float16* __restrict__ alpha16,
                                              const _Float16* __restrict__ PT,
                                              const float* __restrict__ vpb,
                                              _Float16* __restrict__ v1a,
                                              _Float16* __restrict__ v1b) {
    __shared__ __align__(16) _Float16 As[128][64];
    __shared__ __align__(16) _Float16 Bs[128][64];
    const int tid = threadIdx.x;
    const int wid = tid >> 6;
    const int lane = tid & 63;
    const int swz = xcd_swz(gridDim.x * gridDim.y);
    const int brow = (swz / gridDim.x) * 128;
    const int bcol = (swz % gridDim.x) * 128;
    const int b = brow >> 12;
    const _Float16* Bt = PT + (size_t)b * HMm * 64;
    _Float16* Cb = (brow < 8192) ? v1a : v1b;
    const int rowoff = (brow < 8192) ? brow : brow - 8192;
    const int wr = (wid >> 1) * 64;
    const int wc = (wid & 1) * 64;

    f32x4 acc[4][4];
#pragma unroll
    for (int m = 0; m < 4; ++m)
#pragma unroll
        for (int n = 0; n < 4; ++n)
            acc[m][n] = f32x4{0.f, 0.f, 0.f, 0.f};

    const int lrow = lane >> 3;
    const int lcol = (lane & 7) * 8;
    const int fr = lane & 15;
    const int fk = (lane >> 4) * 8;

#pragma unroll
    for (int i = 0; i < 4; ++i) {
        int seg = wid * 4 + i;
        const _Float16* g = alpha16 + (size_t)(brow + seg * 8 + lrow) * 64 + lcol;
        __builtin_amdgcn_global_load_lds(
            (const __attribute__((address_space(1))) void*)g,
            (__attribute__((address_space(3))) void*)&As[seg * 8][0], 16, 0, 0);
    }
#pragma unroll
    for (int i = 0; i < 4; ++i) {
        int seg = wid * 4 + i;
        const _Float16* g = Bt + (size_t)(bcol + seg * 8 + lrow) * 64 + lcol;
        __builtin_amdgcn_global_load_lds(
            (const __attribute__((address_space(1))) void*)g,
            (__attribute__((address_space(3))) void*)&Bs[seg * 8][0], 16, 0, 0);
    }
    __syncthreads();
#pragma unroll
    for (int kb = 0; kb < 2; ++kb) {
        f16x8 af[4], bf[4];
#pragma unroll
        for (int m = 0; m < 4; ++m)
            af[m] = *(const f16x8*)&As[wr + m * 16 + fr][kb * 32 + fk];
#pragma unroll
        for (int n = 0; n < 4; ++n)
            bf[n] = *(const f16x8*)&Bs[wc + n * 16 + fr][kb * 32 + fk];
#pragma unroll
        for (int m = 0; m < 4; ++m)
#pragma unroll
            for (int n = 0; n < 4; ++n)
                acc[m][n] = __builtin_amdgcn_mfma_f32_16x16x32_f16(af[m], bf[n], acc[m][n], 0, 0, 0);
    }

    const int crow = (lane >> 4) * 4;
#pragma unroll
    for (int m = 0; m < 4; ++m) {
        int row0 = rowoff + wr + m * 16 + crow;
#pragma unroll
        for (int n = 0; n < 4; ++n) {
            int col = bcol + wc + n * 16 + fr;
            float bv = vpb[col];
#pragma unroll
            for (int r = 0; r < 4; ++r) {
                float v = acc[m][n][r] + bv;
                Cb[(size_t)(row0 + r) * HMm + col] = (_Float16)gelu_f(v);
            }
        }
    }
}

// ---------------- K11: 256x256 GEMM, BK=64 ring-2, 4-phase (m201-class schedule) ------
template <int OUT_F16>
__global__ __launch_bounds__(512, 2) void hgemm8_k(const _Float16* __restrict__ A0,
                                                   const _Float16* __restrict__ A1,
                                                   int splitrow,
                                                   const _Float16* __restrict__ Bt,
                                                   const float* __restrict__ bias,
                                                   void* __restrict__ Cv,
                                                   int M, int N, int K) {
    __shared__ __align__(16) _Float16 As[2][256][64];   // 64 KB
    __shared__ __align__(16) _Float16 Bs[2][256][64];   // 64 KB
    const int tid = threadIdx.x;
    const int wid = tid >> 6;            // 0..7
    const int lane = tid & 63;
    const int swz = xcd_swz(gridDim.x * gridDim.y);
    const int brow = (swz / gridDim.x) * 256;
    const int bcol = (swz % gridDim.x) * 256;
    const _Float16* Ab = (brow < splitrow) ? A0 : A1;
    const int arow0 = brow - ((brow < splitrow) ? 0 : splitrow);
    const int wm = wid >> 2;             // 0..1 -> 128-row half
    const int wn = wid & 3;              // 0..3 -> 64-col quarter

    const int srow = lane >> 3;                        // 0..7
    const int scol = ((lane & 7) ^ (lane >> 3)) * 8;   // f16 elems
    const int fr = lane & 15;
    const int fk0 = (((lane >> 4) ^ (lane & 7))) * 8;
    const int fk1 = (((4 + (lane >> 4)) ^ (lane & 7))) * 8;
    const int crow = (lane >> 4) * 4;

    const int nk = K >> 6;

    f32x4 acc[8][4];
#pragma unroll
    for (int m = 0; m < 8; ++m)
#pragma unroll
        for (int n = 0; n < 4; ++n)
            acc[m][n] = f32x4{0.f, 0.f, 0.f, 0.f};

    auto stage = [&](int t) {
        const int slot = t & 1;
        const size_t kk = (size_t)t << 6;
#pragma unroll
        for (int j = 0; j < 4; ++j) {
            const _Float16* ga = Ab + (size_t)(arow0 + j * 64 + wid * 8 + srow) * K + kk + scol;
            __builtin_amdgcn_global_load_lds(
                (const __attribute__((address_space(1))) void*)ga,
                (__attribute__((address_space(3))) void*)&As[slot][j * 64 + wid * 8][0], 16, 0, 0);
        }
#pragma unroll
        for (int j = 0; j < 4; ++j) {
            const _Float16* gb = Bt + (size_t)(bcol + j * 64 + wid * 8 + srow) * K + kk + scol;
            __builtin_amdgcn_global_load_lds(
                (const __attribute__((address_space(1))) void*)gb,
                (__attribute__((address_space(3))) void*)&Bs[slot][j * 64 + wid * 8][0], 16, 0, 0);
        }
    };

    stage(0);
    stage(1);

    for (int t = 0; t < nk; ++t) {
        if (t + 1 < nk) asm volatile("s_waitcnt vmcnt(8)" ::: "memory");
        else            asm volatile("s_waitcnt vmcnt(0)" ::: "memory");
        __builtin_amdgcn_sched_barrier(0);
        __builtin_amdgcn_s_barrier();
        __builtin_amdgcn_sched_barrier(0);

        const int slot = t & 1;
        f16x8 af[4][2], bf[4][2];
#pragma unroll
        for (int m = 0; m < 4; ++m) {
            af[m][0] = *(const f16x8*)&As[slot][wm * 128 + m * 16 + fr][fk0];
            af[m][1] = *(const f16x8*)&As[slot][wm * 128 + m * 16 + fr][fk1];
        }
#pragma unroll
        for (int n = 0; n < 2; ++n) {
            bf[n][0] = *(const f16x8*)&Bs[slot][wn * 64 + n * 16 + fr][fk0];
            bf[n][1] = *(const f16x8*)&Bs[slot][wn * 64 + n * 16 + fr][fk1];
        }
        __builtin_amdgcn_sched_barrier(0);
        __builtin_amdgcn_s_barrier();
        asm volatile("s_waitcnt lgkmcnt(0)" ::: "memory");
        __builtin_amdgcn_sched_barrier(0);
        __builtin_amdgcn_s_setprio(1);
#pragma unroll
        for (int m = 0; m < 4; ++m)
#pragma unroll
            for (int n = 0; n < 2; ++n)
#pragma unroll
                for (int kk = 0; kk < 2; ++kk)
                    acc[m][n] = __builtin_amdgcn_mfma_f32_16x16x32_f16(af[m][kk], bf[n][kk], acc[m][n], 0, 0, 0);
        __builtin_amdgcn_s_setprio(0);
        __builtin_amdgcn_sched_barrier(0);
#pragma unroll
        for (int n = 2; n < 4; ++n) {
            bf[n][0] = *(const f16x8*)&Bs[slot][wn * 64 + n * 16 + fr][fk0];
            bf[n][1] = *(const f16x8*)&Bs[slot][wn * 64 + n * 16 + fr][fk1];
        }
        __builtin_amdgcn_sched_barrier(0);
        __builtin_amdgcn_s_barrier();
        asm volatile("s_waitcnt lgkmcnt(0)" ::: "memory");
        __builtin_amdgcn_sched_barrier(0);
        __builtin_amdgcn_s_setprio(1);
#pragma unroll
        for (int m = 0; m < 4; ++m)
#pragma unroll
            for (int n = 2; n < 4; ++n)
#pragma unroll
                for (int kk = 0; kk < 2; ++kk)
                    acc[m][n] = __builtin_amdgcn_mfma_f32_16x16x32_f16(af[m][kk], bf[n][kk], acc[m][n], 0, 0, 0);
        __builtin_amdgcn_s_setprio(0);
        __builtin_amdgcn_sched_barrier(0);
#pragma unroll
        for (int m = 0; m < 4; ++m) {
            af[m][0] = *(const f16x8*)&As[slot][wm * 128 + (m + 4) * 16 + fr][fk0];
            af[m][1] = *(const f16x8*)&As[slot][wm * 128 + (m + 4) * 16 + fr][fk1];
        }
        __builtin_amdgcn_sched_barrier(0);
        __builtin_amdgcn_s_barrier();
        asm volatile("s_waitcnt lgkmcnt(0)" ::: "memory");
        __builtin_amdgcn_sched_barrier(0);
        __builtin_amdgcn_s_setprio(1);
#pragma unroll
        for (int m = 0; m < 4; ++m)
#pragma unroll
            for (int n = 0; n < 2; ++n)
#pragma unroll
                for (int kk = 0; kk < 2; ++kk)
                    acc[m + 4][n] = __builtin_amdgcn_mfma_f32_16x16x32_f16(af[m][kk], bf[n][kk], acc[m + 4][n], 0, 0, 0);
        __builtin_amdgcn_s_setprio(0);
        __builtin_amdgcn_sched_barrier(0);
        __builtin_amdgcn_s_barrier();
        __builtin_amdgcn_sched_barrier(0);
        if (t + 2 < nk) stage(t + 2);
        __builtin_amdgcn_s_setprio(1);
#pragma unroll
        for (int m = 0; m < 4; ++m)
#pragma unroll
            for (int n = 2; n < 4; ++n)
#pragma unroll
                for (int kk = 0; kk < 2; ++kk)
                    acc[m + 4][n] = __builtin_amdgcn_mfma_f32_16x16x32_f16(af[m][kk], bf[n][kk], acc[m + 4][n], 0, 0, 0);
        __builtin_amdgcn_s_setprio(0);
        __builtin_amdgcn_sched_barrier(0);
    }

#pragma unroll
    for (int m = 0; m < 8; ++m) {
        int row0 = brow + wm * 128 + m * 16 + crow;
#pragma unroll
        for (int n = 0; n < 4; ++n) {
            int col = bcol + wn * 64 + n * 16 + fr;
            float bv = bias[col];
#pragma unroll
            for (int r = 0; r < 4; ++r) {
                float v = acc[m][n][r] + bv;
                size_t idx = (size_t)(row0 + r) * N + col;
                if (OUT_F16) ((_Float16*)Cv)[idx] = (_Float16)v;
                else ((float*)Cv)[idx] = v;
            }
        }
    }
    (void)M;
}

extern "C" void kernel_launch(void* const* d_in, const int* in_sizes, int n_in,
                              void* d_out, int out_size, void* d_ws, size_t ws_size,
                              hipStream_t stream) {
    const float* x         = (const float*)d_in[0];
    const float* slot_init = (const float*)d_in[1];
    const float* rw1       = (const float*)d_in[2];
    const float* rb1       = (const float*)d_in[3];
    const float* rw2       = (const float*)d_in[4];
    const float* rb2       = (const float*)d_in[5];
    const float* gwi       = (const float*)d_in[6];
    const float* gwh       = (const float*)d_in[7];
    const float* gbi       = (const float*)d_in[8];
    const float* gbh       = (const float*)d_in[9];
    const float* hpw       = (const float*)d_in[10];
    const float* hpb       = (const float*)d_in[11];
    const float* ohw       = (const float*)d_in[12];
    const float* ohb       = (const float*)d_in[13];
    const float* vpw       = (const float*)d_in[14];
    const float* vpb       = (const float*)d_in[15];
    const float* vow       = (const float*)d_in[16];
    const float* vob       = (const float*)d_in[17];
    const float* opw       = (const float*)d_in[18];
    const float* opb       = (const float*)d_in[19];
    const float* tau       = (const float*)d_in[20];
    float* out = (float*)d_out;

    float* ws = (float*)d_ws;
    size_t off = 0;
    auto alloc = [&](size_t nfloats) { float* p = ws + off; off += (nfloats + 63) & ~(size_t)63; return p; };

    float* cb     = alloc(1024);
    float* cbp    = alloc(16 * 1024);
    float* h1     = alloc((size_t)MTOK * 1024);            // fp32; dead after logits:
    _Float16* v1a = (_Float16*)h1;                          //   v1 rows 0..8191 [8192,4096] f16
    float* logits = alloc((size_t)MTOK * 64);
    float* alpha  = alloc((size_t)MTOK * 64);
    _Float16* alpha16 = (_Float16*)alloc((size_t)MTOK * 64 / 2);
    float* slotin = alloc(256 * 64);
    float* part   = alloc((size_t)8 * 64 * 4 * 64);
    float* partw  = alloc(8 * 64 * 4);
    float* Snew   = alloc(256 * 64);
    _Float16* PT   = (_Float16*)alloc((size_t)Bb * HMm * 64 / 2);  // [4,4096,64] f16
    _Float16* vowT = (_Float16*)alloc((size_t)Dd * HMm / 2);       // [1024,4096] f16
    _Float16* opwT = (_Float16*)alloc((size_t)Dd * Dd / 2);        // [1024,1024] f16
    _Float16* v2f16 = (_Float16*)alloc((size_t)MTOK * Dd / 2);     // [16384,1024] f16
    _Float16* w1hiT = (_Float16*)alloc((size_t)Dd * Dd / 2);
    _Float16* w1loT = (_Float16*)alloc((size_t)Dd * Dd / 2);

    // d_out scratch: xhi/xlo before hgemm4p (xhi also read by pool); v1b after vgen.
    _Float16* xhi = (_Float16*)d_out;
    _Float16* xlo = xhi + (size_t)MTOK * Dd;
    _Float16* v1b = (_Float16*)d_out;

    // ---- routing: pre-split x + deep-pipelined 4-plane split-fp16 GEMM + fp32 logits --
    cb_part_k<<<dim3(4, 16), 256, 0, stream>>>(slot_init, rw1, cbp);
    cb_comb_k<<<4, 256, 0, stream>>>(cbp, cb);
    wsplitT_k<<<dim3(Dd / 32, Dd / 32), 256, 0, stream>>>(rw1, w1hiT, w1loT);
    xsplit_k<<<(MTOK * Dd) / (256 * 8), 256, 0, stream>>>(x, xhi, xlo);
    hgemm4p_k<<<dim3(Dd / 256, MTOK / 256), 512, 0, stream>>>(
        xhi, xlo, w1hiT, w1loT, rb1, cb, h1, MTOK, Dd, Dd);
    logits2_k<<<MTOK / 64, 256, 0, stream>>>(h1, rw2, rb2, tau, logits);
    topk_k<<<MTOK / 4, 256, 0, stream>>>(logits, alpha, alpha16);

    // ---- weight transposes (fp32 -> fp16 [N,K]) ----
    transp_f16_k<<<dim3(Dd / 32, HMm / 32), 256, 0, stream>>>(vow, vowT, HMm, Dd);
    transp_f16_k<<<dim3(Dd / 32, Dd / 32), 256, 0, stream>>>(opw, opwT, Dd, Dd);

    // ---- slot pooling (f16 x) + GRU + slot MLP ----
    pool_part_k<<<dim3(64, 8), 256, 0, stream>>>(xhi, alpha, part, partw);
    pool_comb_k<<<64, 256, 0, stream>>>(part, partw, slotin);
    gru_k<<<256, 64, 0, stream>>>(slotin, slot_init, gwi, gwh, gbi, gbh,
                                  hpw, hpb, ohw, ohb, Snew);

    // ---- P[b] = S_emb[b] @ vpw (stored transposed f16 [b][j][hs]) ----
    pmat_k<<<dim3(HMm / 256, Hh), 256, 0, stream>>>(Snew, vpw, PT);

    // ---- value MLP: vgen (K=64), then BK=64 4-phase 256^2 GEMM2 + GEMM3 ----
    vgen_k<<<dim3(HMm / 128, MTOK / 128), 256, 0, stream>>>(
        alpha16, PT, vpb, v1a, v1b);
    hgemm8_k<1><<<dim3(Dd / 256, MTOK / 256), 512, 0, stream>>>(
        v1a, v1b, 8192, vowT, vob, v2f16, MTOK, Dd, HMm);
    hgemm8_k<0><<<dim3(Dd / 256, MTOK / 256), 512, 0, stream>>>(
        v2f16, v2f16, MTOK, opwT, opb, out, MTOK, Dd, Dd);

    (void)in_sizes; (void)n_in; (void)out_size; (void)ws_size;
}